// Round 9
// baseline (35.952 us; speedup 1.0000x reference)
//
#include <hip/hip_runtime.h>

// ECT: x[N,3] f32, v[3,64] f32, batch[N] int32 (sorted, 64 batches)
// out[64,64,64] f32 = cumsum over bins of per-(batch,bin,dir) histogram.
// Single compute kernel: per-block LDS histogram (wave-wide ds_add, the
// structural floor: 1 atomic/point), block-local batch-boundary detection
// (no init kernel), fused local-cumsum flush via exact f32 atomics.
// Zeroing of d_out is a hipMemsetAsync node (graph-capture-safe).
#define RES 64
#define TD 64
#define NB 64
#define BLK 1024            // 16 waves per block
#define WAVES 16
#define CHUNK 2048          // points per block (flat grid: N/CHUNK blocks)

__global__ __launch_bounds__(BLK) void ect_hist_kernel(
    const float* __restrict__ x, const float* __restrict__ v,
    const int* __restrict__ batch, float* __restrict__ out, int N)
{
    const int start = blockIdx.x * CHUNK;         // flat, perfectly balanced
    const int stop  = min(start + CHUNK, N);
    if (start >= N) return;
    const int len = stop - start;

    __shared__ unsigned hist[2][RES * TD];        // 32 KB, 2 blocks/CU (threads-capped)
    __shared__ unsigned col_part[TD][17];         // prefix scratch (odd stride)
    __shared__ int      bchunk[CHUNK];            // 8 KB: this block's batch ids
    __shared__ unsigned bmask[CHUNK / 32];        // segment-boundary bitmask

    const int t = threadIdx.x & 63;               // lane id = direction
    const int w = threadIdx.x >> 6;               // wave id 0..15
    unsigned* __restrict__ hwt = &hist[w >> 3][t];// waves 0-7 -> A, 8-15 -> B
    const float S = 64.0f / 2.2f;                 // RES / (2*RADIUS)
    const float v0S = v[t] * S;
    const float v1S = v[TD + t] * S;
    const float v2S = v[2 * TD + t] * S;
    // bin = floor(x·v * S + 32), clipped to [0,63]

    // ---- block-local segment detection (replaces init-kernel offs) ----
    if (threadIdx.x < CHUNK / 32) bmask[threadIdx.x] = 0u;
    for (int i = threadIdx.x; i < len; i += BLK) bchunk[i] = batch[start + i];
    __syncthreads();
    for (int i = threadIdx.x; i < len; i += BLK) {
        bool bd = (i == len - 1) || (bchunk[i] != bchunk[i + 1]);
        if (bd) atomicOr(&bmask[i >> 5], 1u << (i & 31));  // rare: ~2/block
    }
    __syncthreads();

    // point j's coord k at flat tile offset q=3j+k -> register q>>6, lane q&63
    // (compile-time constants after full unroll -> v_readlane broadcast).
#define SELREG(q, r0, r1, r2) ((q) < 64 ? (r0) : ((q) < 128 ? (r1) : (r2)))
#define RD(q, r0, r1, r2) __uint_as_float(__builtin_amdgcn_readlane(           \
        __float_as_uint(SELREG(q, r0, r1, r2)), (q) & 63))
#define PROC1(j, r0, r1, r2) {                                                 \
        float x0 = RD(3*(j), r0,r1,r2), x1 = RD(3*(j)+1, r0,r1,r2),            \
              x2 = RD(3*(j)+2, r0,r1,r2);                                      \
        float f = fmaf(x0, v0S, fmaf(x1, v1S, fmaf(x2, v2S, 32.0f)));          \
        f = __builtin_amdgcn_fmed3f(f, 0.0f, 63.0f);                           \
        int bin = (int)f;                                                      \
        atomicAdd(hwt + (bin << 6), 1u); }

    int seg = start;
    while (seg < stop) {                          // one iter per batch segment
        // next boundary at relative index >= (seg-start): guaranteed set bit
        int word = (seg - start) >> 5;
        unsigned m = bmask[word] & (0xFFFFFFFFu << ((seg - start) & 31));
        while (m == 0u) m = bmask[++word];
        const int bpos = (word << 5) + (__ffs(m) - 1);   // last idx of segment
        const int segend = start + bpos + 1;
        const int b = bchunk[bpos];               // uniform LDS broadcast

        for (int i = threadIdx.x; i < 2 * RES * TD; i += BLK) hist[0][i] = 0u;
        __syncthreads();

        const int npts = segend - seg;
        const int nf = npts >> 6;                 // full 64-point tiles

        // software-pipelined full tiles: issue next tile's loads, then
        // process current tile from registers (~1300 cyc covers VMEM latency)
        float c0, c1, c2, n0, n1, n2;
        int tl = w;
        if (tl < nf) {
            const int fb = 3 * (seg + (tl << 6)) + t;
            c0 = x[fb]; c1 = x[fb + 64]; c2 = x[fb + 128];
        }
        for (; tl < nf; tl += WAVES) {
            const int tn = tl + WAVES;
            if (tn < nf) {                        // prefetch next tile (uniform)
                const int fb = 3 * (seg + (tn << 6)) + t;
                n0 = x[fb]; n1 = x[fb + 64]; n2 = x[fb + 128];
            }
            #pragma unroll
            for (int j = 0; j < 64; ++j) PROC1(j, c0, c1, c2);
            if (tn < nf) { c0 = n0; c1 = n1; c2 = n2; }
        }

        // ragged segment-tail tile (at most one), owned by wave (nf mod 16)
        const int rem = npts & 63;
        if (rem && w == (nf & (WAVES - 1))) {
            const int fb = 3 * (seg + (nf << 6)) + t;
            const int lim = 3 * segend;
            float l0 = (fb       < lim) ? x[fb]       : 0.0f;
            float l1 = (fb +  64 < lim) ? x[fb +  64] : 0.0f;
            float l2 = (fb + 128 < lim) ? x[fb + 128] : 0.0f;
            #pragma unroll
            for (int j = 0; j < 64; ++j) {
                if (j < rem) PROC1(j, l0, l1, l2);   // wave-uniform guard
            }
        }
        __syncthreads();

        // Fused flush: local cumsum over bins, then exact f32 atomics.
        // Wave w's lane t handles column t, bins [4w, 4w+4).
        unsigned vals[4];
        {
            unsigned s = 0;
            #pragma unroll
            for (int i = 0; i < 4; ++i) {
                int r = (w << 2) + i;
                s += hist[0][(r << 6) + t] + hist[1][(r << 6) + t];
                vals[i] = s;                      // inclusive prefix of my 4
            }
            col_part[t][w] = s;                   // my column-segment total
        }
        __syncthreads();
        {
            unsigned off = 0;
            for (int j = 0; j < w; ++j) off += col_part[t][j];  // uniform trip
            float* __restrict__ gb = out + b * (RES * TD) + t;
            #pragma unroll
            for (int i = 0; i < 4; ++i) {
                int r = (w << 2) + i;
                atomicAdd(gb + (r << 6), (float)(vals[i] + off)); // coalesced
            }
        }
        if (segend < stop) __syncthreads();       // before re-zeroing hist
        seg = segend;
    }
#undef PROC1
#undef RD
#undef SELREG
}

extern "C" void kernel_launch(void* const* d_in, const int* in_sizes, int n_in,
                              void* d_out, int out_size, void* d_ws, size_t ws_size,
                              hipStream_t stream) {
    const float* x = (const float*)d_in[0];          // [N,3]
    const float* v = (const float*)d_in[1];          // [3,64]
    const int* batch = (const int*)d_in[2];          // [N] int32, sorted
    const int N = in_sizes[2];

    // zero the accumulator: memset node, graph-capture-safe
    hipMemsetAsync(d_out, 0, (size_t)out_size * sizeof(float), stream);

    const int nblocks = (N + CHUNK - 1) / CHUNK;     // 512 for N=1M
    ect_hist_kernel<<<nblocks, BLK, 0, stream>>>(x, v, batch, (float*)d_out, N);
}

// Round 10
// 32.904 us; speedup vs baseline: 1.0926x; 1.0926x over previous
//
#include <hip/hip_runtime.h>

// ECT: x[N,3] f32, v[3,64] f32, batch[N] int32 (sorted, 64 batches)
// out[64,64,64] f32 = cumsum over bins of per-(batch,bin,dir) histogram.
// init: zero d_out + PARALLEL batch-boundary detection (offs[65]).
// hist: per-block LDS histogram (wave-wide ds_add = 1 atomic/point, the
// structural floor), fused local-cumsum flush via exact f32 atomics.
#define RES 64
#define TD 64
#define NB 64
#define BLK 1024            // 16 waves per block
#define WAVES 16
#define CHUNK 2048          // points per block (flat grid: N/CHUNK blocks)

// grid: 1024 blocks x 256 threads = 262144 threads.
// Each thread zeroes one float of out AND scans a strided slice of batch
// for boundaries; each offs slot has exactly one writer (race-free).
__global__ __launch_bounds__(256) void ect_init_kernel(
    const int* __restrict__ batch, int N,
    float* __restrict__ out, int* __restrict__ offs)
{
    const int gid = blockIdx.x * 256 + threadIdx.x;
    out[gid] = 0.0f;                              // 262144 floats = 1 MB

    if (gid == 0) {
        int b0 = batch[0];
        for (int bb = 0; bb <= b0; ++bb) offs[bb] = 0;   // leading (empty) ids
    }
    for (int i = gid; i < N; i += 262144) {
        int b0 = batch[i];
        int b1 = (i + 1 < N) ? batch[i + 1] : NB;        // sentinel closes tail
        if (b0 != b1) {
            for (int bb = b0 + 1; bb <= b1; ++bb) offs[bb] = i + 1;  // ~63 total
        }
    }
}

__global__ __launch_bounds__(BLK) void ect_hist_kernel(
    const float* __restrict__ x, const float* __restrict__ v,
    const int* __restrict__ offs, float* __restrict__ out, int N)
{
    const int start = blockIdx.x * CHUNK;         // flat, perfectly balanced
    const int stop  = min(start + CHUNK, N);
    if (start >= N) return;

    __shared__ unsigned hist[2][RES * TD];        // 32 KB, 2 blocks/CU
    __shared__ unsigned col_part[TD][17];         // prefix scratch (odd stride)

    const int t = threadIdx.x & 63;               // lane id = direction
    const int w = threadIdx.x >> 6;               // wave id 0..15
    unsigned* __restrict__ hwt = &hist[w >> 3][t];// waves 0-7 -> A, 8-15 -> B
    const float S = 64.0f / 2.2f;                 // RES / (2*RADIUS)
    const float v0S = v[t] * S;
    const float v1S = v[TD + t] * S;
    const float v2S = v[2 * TD + t] * S;
    // bin = floor(x·v * S + 32), clipped to [0,63]

    // batch of first point: largest b with offs[b] <= start (uniform)
    int lo = 0, hi = NB;
    while (lo < hi) {
        int mid = (lo + hi + 1) >> 1;
        if (offs[mid] <= start) lo = mid; else hi = mid - 1;
    }
    int b = lo;

    // point j's coord k at flat tile offset q=3j+k -> register q>>6, lane q&63
    // (compile-time constants after full unroll -> v_readlane broadcast).
#define SELREG(q, r0, r1, r2) ((q) < 64 ? (r0) : ((q) < 128 ? (r1) : (r2)))
#define RD(q, r0, r1, r2) __uint_as_float(__builtin_amdgcn_readlane(           \
        __float_as_uint(SELREG(q, r0, r1, r2)), (q) & 63))
#define PROC1(j, r0, r1, r2) {                                                 \
        float x0 = RD(3*(j), r0,r1,r2), x1 = RD(3*(j)+1, r0,r1,r2),            \
              x2 = RD(3*(j)+2, r0,r1,r2);                                      \
        float f = fmaf(x0, v0S, fmaf(x1, v1S, fmaf(x2, v2S, 32.0f)));          \
        f = __builtin_amdgcn_fmed3f(f, 0.0f, 63.0f);                           \
        int bin = (int)f;                                                      \
        atomicAdd(hwt + (bin << 6), 1u); }

    int seg = start;
    while (seg < stop) {                          // one iter per batch segment
        while (offs[b + 1] <= seg) ++b;           // skip empty batches (uniform)
        const int segend = min(stop, offs[b + 1]);

        for (int i = threadIdx.x; i < 2 * RES * TD; i += BLK) hist[0][i] = 0u;
        __syncthreads();

        const int npts = segend - seg;
        const int nf = npts >> 6;                 // full 64-point tiles

        // software-pipelined full tiles: issue next tile's loads, then
        // process current tile from registers (~1300 cyc covers VMEM latency)
        float c0, c1, c2, n0, n1, n2;
        int tl = w;
        if (tl < nf) {
            const int fb = 3 * (seg + (tl << 6)) + t;
            c0 = x[fb]; c1 = x[fb + 64]; c2 = x[fb + 128];
        }
        for (; tl < nf; tl += WAVES) {
            const int tn = tl + WAVES;
            if (tn < nf) {                        // prefetch next tile (uniform)
                const int fb = 3 * (seg + (tn << 6)) + t;
                n0 = x[fb]; n1 = x[fb + 64]; n2 = x[fb + 128];
            }
            #pragma unroll
            for (int j = 0; j < 64; ++j) PROC1(j, c0, c1, c2);
            if (tn < nf) { c0 = n0; c1 = n1; c2 = n2; }
        }

        // ragged segment-tail tile (at most one), owned by wave (nf mod 16)
        const int rem = npts & 63;
        if (rem && w == (nf & (WAVES - 1))) {
            const int fb = 3 * (seg + (nf << 6)) + t;
            const int lim = 3 * segend;
            float l0 = (fb       < lim) ? x[fb]       : 0.0f;
            float l1 = (fb +  64 < lim) ? x[fb +  64] : 0.0f;
            float l2 = (fb + 128 < lim) ? x[fb + 128] : 0.0f;
            #pragma unroll
            for (int j = 0; j < 64; ++j) {
                if (j < rem) PROC1(j, l0, l1, l2);   // wave-uniform guard
            }
        }
        __syncthreads();

        // Fused flush: local cumsum over bins, then exact f32 atomics.
        // Wave w's lane t handles column t, bins [4w, 4w+4).
        unsigned vals[4];
        {
            unsigned s = 0;
            #pragma unroll
            for (int i = 0; i < 4; ++i) {
                int r = (w << 2) + i;
                s += hist[0][(r << 6) + t] + hist[1][(r << 6) + t];
                vals[i] = s;                      // inclusive prefix of my 4
            }
            col_part[t][w] = s;                   // my column-segment total
        }
        __syncthreads();
        {
            unsigned off = 0;
            for (int j = 0; j < w; ++j) off += col_part[t][j];  // uniform trip
            float* __restrict__ gb = out + b * (RES * TD) + t;
            #pragma unroll
            for (int i = 0; i < 4; ++i) {
                int r = (w << 2) + i;
                atomicAdd(gb + (r << 6), (float)(vals[i] + off)); // coalesced
            }
        }
        if (segend < stop) __syncthreads();       // before re-zeroing hist
        seg = segend;
    }
#undef PROC1
#undef RD
#undef SELREG
}

extern "C" void kernel_launch(void* const* d_in, const int* in_sizes, int n_in,
                              void* d_out, int out_size, void* d_ws, size_t ws_size,
                              hipStream_t stream) {
    const float* x = (const float*)d_in[0];          // [N,3]
    const float* v = (const float*)d_in[1];          // [3,64]
    const int* batch = (const int*)d_in[2];          // [N] int32, sorted
    const int N = in_sizes[2];
    int* offs = (int*)d_ws;                          // 65 ints of scratch

    ect_init_kernel<<<1024, 256, 0, stream>>>(batch, N, (float*)d_out, offs);

    const int nblocks = (N + CHUNK - 1) / CHUNK;     // 512 for N=1M
    ect_hist_kernel<<<nblocks, BLK, 0, stream>>>(x, v, offs, (float*)d_out, N);
}